// Round 7
// baseline (324.161 us; speedup 1.0000x reference)
//
#include <hip/hip_runtime.h>
#include <stdint.h>

// FlowNetC correlation, bf16 MFMA banded-GEMM, v10.
// out[b, iy*21+ix, h, w] = (1/256) sum_c in1[b,c,h,w] * in2[b,c,h+dy,w+dx]
// Parity split w=2u+r, w'=2v+r, v=u+ix-10 -> banded Gram per (b, h-pair, r).
// ws layout (both inputs): [inp][b][h][row=r*48+u][c 256] bf16; in1 pre-scaled
// by 1/256 in pack (exact).
//
// v10 = v9's lean disjoint partition + v7.1's coalesced LDS epilogue:
//  - v9 (scattered dword stores, no LDS) proved stores MUST be assembled in
//    LDS: 4 scalar stores/wave-iter -> ~200 line txns -> 154us, all pipes idle.
//  - 6 waves/block = (band-tile tt 0..2) x (parity rr), K=256/wave. Each
//    (u,v) Gram cell belongs to exactly one tt -> waves write DISJOINT sO
//    cells (no kh-sum, no read-modify, single sO copy, 5.9KB LDS).
//  - One raw s_barrier + lgkmcnt(0) per iteration (T4): A-prefetch global
//    loads stay in flight across the barrier, counted vmcnt at use.
//  - Pipelined epilogue: issue sO reads of iter i-1, run iter i's MFMAs,
//    then finish adds + nt-store (LDS read latency hidden under MFMA).
//  - Edge waves (tile fully out of image) stay resident (barrier safety),
//    skip compute, share epilogue work.

#define CP    256            // c row (512 B)
#define WSROW (96 * CP)      // 24576 bf16 = 49152 B per (input,b,h)

typedef __bf16 bf16x8 __attribute__((ext_vector_type(8)));
typedef float  f32x4  __attribute__((ext_vector_type(4)));

// ---------------- Phase 1: pack fp32 -> bf16, direct (no LDS)
// grid 1024 = [inp(2)][b(8)][h(64)], block 384 = x(96) x cig(4)
__global__ __launch_bounds__(384) void pack_kernel(
    const float* __restrict__ in1, const float* __restrict__ in2,
    __bf16* __restrict__ ws) {
  const int id = blockIdx.x;
  const float* src = (id >> 9) ? in2 : in1;
  const float scale = (id >> 9) ? 1.0f : 0.00390625f;   // in1 *= 1/256 (exact)
  const int bh = id & 511;
  const int b = bh >> 6, h = bh & 63;
  const int t = threadIdx.x;
  const int x = t >> 2, cig = t & 3;            // 4 lanes share one x
  const int row = (x & 1) * 48 + (x >> 1);      // parity-major row index

  const size_t sbase = (size_t)b * (256 * 64 * 96) + (size_t)h * 96 + x;
  __bf16* dst = ws + (size_t)id * WSROW + (size_t)row * CP;

#pragma unroll
  for (int g = 0; g < 8; ++g) {                 // c-chunks of 32
    const int cb = g * 32 + cig * 8;
    float v[8];
#pragma unroll
    for (int k = 0; k < 8; ++k)
      v[k] = src[sbase + (size_t)(cb + k) * (64 * 96)];
    bf16x8 o;
#pragma unroll
    for (int k = 0; k < 8; ++k) o[k] = (__bf16)(v[k] * scale);
    *(bf16x8*)(dst + cb) = o;                   // 4 lanes -> one full 64B line
  }
}

// ---------------- Phase 2: MFMA band-GEMM
// grid 1536 = [u0i(3)][h2(64)][b(8)], block 384 = 6 waves = (tt x rr)
__global__ __launch_bounds__(384, 2) void corr_mfma(
    const __bf16* __restrict__ ws, float* __restrict__ out) {
  const int gid = blockIdx.x;
  const int b = gid & 7;               // XCD affinity (blockIdx%8 -> XCD)
  const int rest = gid >> 3;
  const int h2 = rest & 63;            // in2 row this block correlates against
  const int u0i = rest >> 6;           // 0..2 : u-tile (w-slice [32*u0i, +32))
  const int u0 = u0i << 4;
  const int t = threadIdx.x;
  const int wv = t >> 6;               // 0..5
  const int rr = wv & 1;               // parity
  const int tt = wv >> 1;              // band tile: v in [u0+16(tt-1), +16)
  const int lane = t & 63;
  const int col = lane & 15, quad = lane >> 4;

  const __bf16* ws1 = ws;
  const __bf16* ws2 = ws + (size_t)512 * WSROW;

  __shared__ float sO[2][21][35];      // 5.9 KB; single copy (disjoint writes)

  // Zero both buffers once; never-covered cells are i-invariant zeros.
  for (int idx = t; idx < 2 * 21 * 35; idx += 384) ((float*)sO)[idx] = 0.0f;

  // Zero-fill output rows whose in2 source row h2+dy is out of image.
  if (t < 168) {
    const f32x4 z4 = {0.f, 0.f, 0.f, 0.f};
    const int zix = t >> 3, zg = t & 7;
    for (int i = 0; i < 21; ++i) {
      int hh = h2 + 2 * i - 20;
      if (hh < 0 || hh >= 64) {
        float* p = out + ((size_t)(b * 441 + i * 21 + zix) * 64 + h2) * 96
                   + 2 * u0 + 4 * zg;
        __builtin_nontemporal_store(z4, (f32x4*)p);
      }
    }
  }

  // Edge waves: tile fully outside image (v<0 or v>=48). Stay resident.
  const bool active = !((u0i == 0 && tt == 0) || (u0i == 2 && tt == 2));

  // B fragments -> registers, once. v in [0,48) for active waves.
  bf16x8 bfrag[8];
  if (active) {
    const int v = u0 + 16 * (tt - 1) + col;
    const __bf16* p = ws2 + (size_t)(b * 64 + h2) * WSROW
                      + (size_t)(rr * 48 + v) * CP + quad * 8;
#pragma unroll
    for (int s = 0; s < 8; ++s) bfrag[s] = *(const bf16x8*)(p + 32 * s);
  }

  // Per-lane LDS scatter offsets + predicates (i-invariant, disjoint per wave)
  int loff[4];
  bool sval[4];
#pragma unroll
  for (int reg = 0; reg < 4; ++reg) {
    const int du = quad * 4 + reg;
    const int ix = (tt - 1) * 16 + col - du + 10;
    sval[reg] = active && (ix >= 0 && ix < 21);
    loff[reg] = ix * 35 + 2 * du + rr;          // local w = 2du+rr in [0,32)
  }

  const int i_lo = max(0, (h2 - 42) >> 1);      // block-uniform
  const int i_hi = min(20, (h2 + 20) >> 1);

  __syncthreads();                              // sO init visible

  const int aoff = (rr * 48 + u0 + col) * CP + quad * 8;

  auto loadA = [&](bf16x8(&a)[8], int i) {
    const __bf16* p = ws1 + (size_t)(b * 64 + (h2 - 2 * i + 20)) * WSROW + aoff;
#pragma unroll
    for (int s = 0; s < 8; ++s) a[s] = *(const bf16x8*)(p + 32 * s);
  };

  auto mfma8 = [&](const bf16x8(&a)[8], f32x4& accO) {
    f32x4 A = {0.f, 0.f, 0.f, 0.f};
    f32x4 B = {0.f, 0.f, 0.f, 0.f};
#pragma unroll
    for (int s = 0; s < 4; ++s) {               // two independent 4-chains
      A = __builtin_amdgcn_mfma_f32_16x16x32_bf16(a[s],     bfrag[s],     A, 0, 0, 0);
      B = __builtin_amdgcn_mfma_f32_16x16x32_bf16(a[s + 4], bfrag[s + 4], B, 0, 0, 0);
    }
    accO = A + B;
  };

  auto scatter = [&](const f32x4& acc, int ob) {
    float* base = &sO[ob][0][0];
#pragma unroll
    for (int reg = 0; reg < 4; ++reg)
      if (sval[reg]) base[loff[reg]] = acc[reg];
  };

  // Epilogue split over 168 threads: ix = t>>3, 4 floats each at 4*(t&7).
  const int eIx = t >> 3, eG = t & 7;
  const bool eAct = (t < 168);

  auto epi_read = [&](int ob, float(&e)[4]) {
    if (eAct) {
#pragma unroll
      for (int k = 0; k < 4; ++k) e[k] = sO[ob][eIx][4 * eG + k];
    }
  };
  auto epi_finish = [&](int i, const float(&e)[4]) {
    if (eAct) {
      f32x4 v = {e[0], e[1], e[2], e[3]};
      const int h = h2 - 2 * i + 20;
      float* p = out + ((size_t)(b * 441 + i * 21) * 64 + h) * 96 + 2 * u0
                 + (size_t)eIx * 6144 + 4 * eG;
      __builtin_nontemporal_store(v, (f32x4*)p);
    }
  };

  auto bar = [&]() {
    asm volatile("s_waitcnt lgkmcnt(0)" ::: "memory");
    __builtin_amdgcn_sched_barrier(0);
    __builtin_amdgcn_s_barrier();
    __builtin_amdgcn_sched_barrier(0);
  };

  // ---- main pipeline. Buffer of iteration i is (i - i_lo) & 1.
  bf16x8 aX[8], aY[8];
  float e[4];
  f32x4 acc;

  if (active) {
    loadA(aX, i_lo);
    if (i_lo < i_hi) loadA(aY, i_lo + 1);
    __builtin_amdgcn_sched_barrier(0);
    mfma8(aX, acc);
    scatter(acc, 0);
  }
  bar();

  for (int i = i_lo + 1; i <= i_hi; ++i) {
    const int par = (i - i_lo) & 1;             // block-uniform
    epi_read(par ^ 1, e);                       // issue sO reads of iter i-1
    if (par) {
      if (active) {
        if (i < i_hi) loadA(aX, i + 1);
        __builtin_amdgcn_sched_barrier(0);
        mfma8(aY, acc);                         // hides LDS-read latency
      }
    } else {
      if (active) {
        if (i < i_hi) loadA(aY, i + 1);
        __builtin_amdgcn_sched_barrier(0);
        mfma8(aX, acc);
      }
    }
    epi_finish(i - 1, e);
    if (active) scatter(acc, par);
    bar();
  }

  // drain last epilogue
  epi_read((i_hi - i_lo) & 1, e);
  epi_finish(i_hi, e);
}

extern "C" void kernel_launch(void* const* d_in, const int* in_sizes, int n_in,
                              void* d_out, int out_size, void* d_ws, size_t ws_size,
                              hipStream_t stream) {
  const float* in1 = (const float*)d_in[0];
  const float* in2 = (const float*)d_in[1];
  float* out = (float*)d_out;
  __bf16* ws = (__bf16*)d_ws;    // 1024 * 24576 bf16 = 50.3 MB

  pack_kernel<<<1024, 384, 0, stream>>>(in1, in2, ws);
  corr_mfma<<<1536, 384, 0, stream>>>(ws, out);
}